// Round 10
// baseline (126.984 us; speedup 1.0000x reference)
//
#include <hip/hip_runtime.h>
#include <hip/hip_bf16.h>

#define BATCH 8
#define SEQ   512
#define DIM   512
#define NL    64

typedef float f32x4 __attribute__((ext_vector_type(4)));

// Kernel 0 — byte-identical to round 9. W[64][1024] -> WT4[hd][k4][l].
__global__ __launch_bounds__(256) void alab_wt(
    const float* __restrict__ W, f32x4* __restrict__ wt4)
{
    const int tid = blockIdx.x * 256 + threadIdx.x;   // 0..16383
    const int l   = tid & 63;
    const int k4  = (tid >> 6) & 127;
    const int hd  = tid >> 13;
    wt4[tid] = *(const f32x4*)(W + (size_t)l * (2 * DIM) + hd * DIM + k4 * 4);
}

// proj v5: lane = l (coalesced WT loads, as v4). Input rows are WAVE-UNIFORM
// (wave w owns rows i0+4w..+3): row base forced to SGPR via readfirstlane so
// the compiler emits s_load (SMEM/K$ pipe) instead of the 4096 per-CU
// ds_read_b128 broadcasts that bound v4 (each moved 1KB for 16 useful B).
// No LDS, no barrier. Per k4-iter: 1 coalesced VMEM (wt) + 4 s_load_dwordx4
// + 16 v_fma (SGPR operand). VALU-bound floor ~3.4 us.
__global__ __launch_bounds__(256) void alab_proj5(
    const float* __restrict__ head, const float* __restrict__ dep,
    const f32x4* __restrict__ wt4, const float* __restrict__ bias,
    float* __restrict__ hbuf, float* __restrict__ dbuf)
{
    const int bid   = blockIdx.x;
    const int hd    = bid & 1;                  // 0 = head->h, 1 = dep->d
    const int itile = (bid >> 1) & 31;
    const int b     = bid >> 6;
    const int i0    = itile * 16;

    const float* src = hd ? dep  : head;
    float*       dst = hd ? dbuf : hbuf;

    const int lane = threadIdx.x & 63;          // = l
    const int w    = threadIdx.x >> 6;          // wave -> rows i0+4w..+3

    const int iw = __builtin_amdgcn_readfirstlane(i0 + w * 4);  // SGPR row idx
    const float* r0 = src + ((size_t)b * SEQ + iw + 0) * DIM;
    const float* r1 = src + ((size_t)b * SEQ + iw + 1) * DIM;
    const float* r2 = src + ((size_t)b * SEQ + iw + 2) * DIM;
    const float* r3 = src + ((size_t)b * SEQ + iw + 3) * DIM;

    const f32x4* wbase = wt4 + (size_t)hd * (128 * 64) + lane;

    f32x4 a0 = {0,0,0,0}, a1 = {0,0,0,0}, a2 = {0,0,0,0}, a3 = {0,0,0,0};
    #pragma unroll 4
    for (int k4 = 0; k4 < 128; ++k4) {
        const f32x4 wt = wbase[(size_t)k4 * 64];       // coalesced 1KB/wave
        const f32x4 s0 = *(const f32x4*)(r0 + k4 * 4); // uniform -> s_load
        const f32x4 s1 = *(const f32x4*)(r1 + k4 * 4);
        const f32x4 s2 = *(const f32x4*)(r2 + k4 * 4);
        const f32x4 s3 = *(const f32x4*)(r3 + k4 * 4);
        a0 += s0 * wt;
        a1 += s1 * wt;
        a2 += s2 * wt;
        a3 += s3 * wt;
    }
    const float bb = hd ? 0.f : bias[lane];            // bias folded into h
    f32x4 r = { a0.x + a0.y + a0.z + a0.w + bb,
                a1.x + a1.y + a1.z + a1.w + bb,
                a2.x + a2.y + a2.z + a2.w + bb,
                a3.x + a3.y + a3.z + a3.w + bb };
    *(f32x4*)(dst + ((size_t)b * NL + lane) * SEQ + iw) = r;
}

// bcast v4 — byte-identical to rounds 6/9.
__global__ __launch_bounds__(256) void alab_bcast4(
    const float* __restrict__ hbuf, const float* __restrict__ dbuf,
    float* __restrict__ out)
{
    __shared__ float sh[SEQ];        // full h row for this (b,l)
    __shared__ f32x4 sd4[SEQ / 4];   // full d row
    const int t  = threadIdx.x;
    const int bl = blockIdx.x;       // b*NL + l, 0..511

    sh[t]                  = hbuf[(size_t)bl * SEQ + t];
    sh[t + 256]            = hbuf[(size_t)bl * SEQ + t + 256];
    ((float*)sd4)[t]       = dbuf[(size_t)bl * SEQ + t];
    ((float*)sd4)[t + 256] = dbuf[(size_t)bl * SEQ + t + 256];
    __syncthreads();

    const int j4 = t & 127;                     // fixed float4 column
    const int rh = t >> 7;                      // row parity (0/1)
    const f32x4 dreg = sd4[j4];                 // loop-invariant
    f32x4* ob = (f32x4*)out + (size_t)bl * SEQ * (SEQ / 4);

    #pragma unroll 8
    for (int ii = 0; ii < SEQ; ii += 2) {
        const int i = ii + rh;
        ob[(size_t)i * (SEQ / 4) + j4] = dreg + sh[i];
    }
}

extern "C" void kernel_launch(void* const* d_in, const int* in_sizes, int n_in,
                              void* d_out, int out_size, void* d_ws, size_t ws_size,
                              hipStream_t stream) {
    const float* head = (const float*)d_in[0];
    const float* dep  = (const float*)d_in[1];
    const float* W    = (const float*)d_in[2];
    const float* bias = (const float*)d_in[3];
    float* out = (float*)d_out;

    const size_t P = (size_t)BATCH * NL * SEQ;           // 262144 floats
    float* hbuf = (float*)d_ws;                          // 1 MiB
    float* dbuf = hbuf + P;                              // 1 MiB
    f32x4* wt4  = (f32x4*)(dbuf + P);                    // 256 KB

    alab_wt   <<<64,         256, 0, stream>>>(W, wt4);
    alab_proj5<<<BATCH * 64, 256, 0, stream>>>(head, dep, wt4, bias, hbuf, dbuf);
    alab_bcast4<<<BATCH * NL, 256, 0, stream>>>(hbuf, dbuf, out);
}

// Round 11
// 110.704 us; speedup vs baseline: 1.1471x; 1.1471x over previous
//
#include <hip/hip_runtime.h>
#include <hip/hip_bf16.h>

#define BATCH 8
#define SEQ   512
#define DIM   512
#define NL    64

typedef float f32x4 __attribute__((ext_vector_type(4)));
using bf16x8 = __attribute__((ext_vector_type(8))) short;   // 8 bf16 = 4 VGPRs

// f32 -> bf16 RNE (bit trick; inputs finite)
static __device__ __forceinline__ unsigned bf1(float f) {
    unsigned u = __builtin_bit_cast(unsigned, f);
    return (u + 0x7FFFu + ((u >> 16) & 1u)) >> 16;
}
static __device__ __forceinline__ unsigned bfpair(float a, float b) {
    return bf1(a) | (bf1(b) << 16);
}

// Kernel 0 v2: W[64][1024] f32 -> Wbf[hd][l][k] bf16 (128 KB, L2-resident).
__global__ __launch_bounds__(256) void alab_wt2(
    const float* __restrict__ W, unsigned short* __restrict__ wbf)
{
    const int tid = blockIdx.x * 256 + threadIdx.x;   // 0..16383
    const int hd  = tid >> 13;
    const int l   = (tid >> 7) & 63;
    const int kc  = (tid & 127) * 4;
    const float4 f = *(const float4*)(W + (size_t)l * (2 * DIM) + hd * DIM + kc);
    uint2 o = { bfpair(f.x, f.y), bfpair(f.z, f.w) };
    *(uint2*)(wbf + ((size_t)hd * NL + l) * DIM + kc) = o;
}

// proj v6 (MFMA): block = (b, itile16, hd), 4 waves. Stage 16 input rows as
// bf16 in LDS (pitch 520 ushorts -> 2-way bank alias = free). Wave w owns
// l in [w*16, w*16+16): 16x16 C tile, K=512 = 16 mfma_f32_16x16x32_bf16.
// A-frag: ds_read_b128 (lane&15 = i-row, (lane>>4)*8 = k-chunk).
// B-frag: 16B/lane direct from L2-resident Wbf (same lane mapping, row = l).
// This removes the structural LDS-broadcast floor of v4 (4096 x 12cyc/CU):
// v6 per CU = 128 ds_read + 128 mfma + staging ~= 2-3 us.
__global__ __launch_bounds__(256) void alab_proj6(
    const float* __restrict__ head, const float* __restrict__ dep,
    const unsigned short* __restrict__ wbf, const float* __restrict__ bias,
    float* __restrict__ hbuf, float* __restrict__ dbuf)
{
    __shared__ __align__(16) unsigned short A_lds[16 * 520];  // 16.25 KB
    const int bid   = blockIdx.x;
    const int hd    = bid & 1;                  // 0 = head->h, 1 = dep->d
    const int itile = (bid >> 1) & 31;
    const int b     = bid >> 6;
    const int i0    = itile * 16;

    const float* src = hd ? dep  : head;
    float*       dst = hd ? dbuf : hbuf;

    // ---- stage A: 16 rows x 512 f32 -> bf16 LDS. Thread u: row u>>6,
    // 8-elem chunk (u&63)*8; wave covers one full 2KB row -> coalesced.
    const float* arow = src + ((size_t)b * SEQ + i0) * DIM;
    #pragma unroll
    for (int u = threadIdx.x; u < 1024; u += 256) {
        const int row = u >> 6, kc = (u & 63) * 8;
        const float* p = arow + row * DIM + kc;
        const float4 f0 = *(const float4*)p;
        const float4 f1 = *(const float4*)(p + 4);
        uint4 wv = { bfpair(f0.x, f0.y), bfpair(f0.z, f0.w),
                     bfpair(f1.x, f1.y), bfpair(f1.z, f1.w) };
        *(uint4*)&A_lds[row * 520 + kc] = wv;
    }
    __syncthreads();

    const int lane = threadIdx.x & 63;
    const int w    = threadIdx.x >> 6;          // wave -> l quadrant
    const int lr   = lane & 15;                 // A: i-row / B: l-row / C: col
    const int kg   = lane >> 4;                 // k-group (8 bf16 each)

    const unsigned short* Ab = &A_lds[lr * 520 + kg * 8];
    const unsigned short* Bb = wbf + ((size_t)hd * NL + w * 16 + lr) * DIM + kg * 8;

    f32x4 acc0 = {0.f, 0.f, 0.f, 0.f}, acc1 = {0.f, 0.f, 0.f, 0.f};
    #pragma unroll
    for (int s = 0; s < 16; s += 2) {           // 2 accumulators for ILP
        const bf16x8 a0 = *(const bf16x8*)(Ab + (s + 0) * 32);
        const bf16x8 b0 = *(const bf16x8*)(Bb + (s + 0) * 32);
        const bf16x8 a1 = *(const bf16x8*)(Ab + (s + 1) * 32);
        const bf16x8 b1 = *(const bf16x8*)(Bb + (s + 1) * 32);
        acc0 = __builtin_amdgcn_mfma_f32_16x16x32_bf16(a0, b0, acc0, 0, 0, 0);
        acc1 = __builtin_amdgcn_mfma_f32_16x16x32_bf16(a1, b1, acc1, 0, 0, 0);
    }
    const f32x4 acc = acc0 + acc1;

    // C layout (m89-verified): col = lane&15 (=l), row = (lane>>4)*4 + reg (=i)
    const int l = w * 16 + lr;
    const int i = i0 + kg * 4;
    const float bb = hd ? 0.f : bias[l];        // bias folded into h
    const f32x4 r = acc + bb;
    *(f32x4*)(dst + ((size_t)b * NL + l) * SEQ + i) = r;
}

// bcast v4 — byte-identical to rounds 6/9.
__global__ __launch_bounds__(256) void alab_bcast4(
    const float* __restrict__ hbuf, const float* __restrict__ dbuf,
    float* __restrict__ out)
{
    __shared__ float sh[SEQ];        // full h row for this (b,l)
    __shared__ f32x4 sd4[SEQ / 4];   // full d row
    const int t  = threadIdx.x;
    const int bl = blockIdx.x;       // b*NL + l, 0..511

    sh[t]                  = hbuf[(size_t)bl * SEQ + t];
    sh[t + 256]            = hbuf[(size_t)bl * SEQ + t + 256];
    ((float*)sd4)[t]       = dbuf[(size_t)bl * SEQ + t];
    ((float*)sd4)[t + 256] = dbuf[(size_t)bl * SEQ + t + 256];
    __syncthreads();

    const int j4 = t & 127;                     // fixed float4 column
    const int rh = t >> 7;                      // row parity (0/1)
    const f32x4 dreg = sd4[j4];                 // loop-invariant
    f32x4* ob = (f32x4*)out + (size_t)bl * SEQ * (SEQ / 4);

    #pragma unroll 8
    for (int ii = 0; ii < SEQ; ii += 2) {
        const int i = ii + rh;
        ob[(size_t)i * (SEQ / 4) + j4] = dreg + sh[i];
    }
}

extern "C" void kernel_launch(void* const* d_in, const int* in_sizes, int n_in,
                              void* d_out, int out_size, void* d_ws, size_t ws_size,
                              hipStream_t stream) {
    const float* head = (const float*)d_in[0];
    const float* dep  = (const float*)d_in[1];
    const float* W    = (const float*)d_in[2];
    const float* bias = (const float*)d_in[3];
    float* out = (float*)d_out;

    const size_t P = (size_t)BATCH * NL * SEQ;           // 262144 floats
    float* hbuf = (float*)d_ws;                          // 1 MiB
    float* dbuf = hbuf + P;                              // 1 MiB
    unsigned short* wbf = (unsigned short*)(dbuf + P);   // 128 KB bf16 W

    alab_wt2  <<<64,         256, 0, stream>>>(W, wbf);
    alab_proj6<<<BATCH * 64, 256, 0, stream>>>(head, dep, wbf, bias, hbuf, dbuf);
    alab_bcast4<<<BATCH * NL, 256, 0, stream>>>(hbuf, dbuf, out);
}